// Round 10
// baseline (478.015 us; speedup 1.0000x reference)
//
#include <hip/hip_runtime.h>
#include <cstddef>
#include <cstdint>

// ---------------- problem constants ----------------
#define HW    512
#define CCH   16
// Role-split conv: 512-thread block = 4 consumer waves + 4 producer waves.
// Each block processes 2 x-adjacent 12x16 tiles with double-buffered staging.
#define TR    12           // tile rows (3 per consumer wave)
#define HTILE 18           // halo cols
#define HTR   14           // halo rows
#define NPIXR 252          // real halo pixels (14*18)
#define NPIXP 254          // padded pixel stride (== 6 mod 8 -> conflict-free writes)
#define NSLOT 12           // uint4 slots per pixel (96 f16 = 8 cins x 12 kv)
#define BUFU  (NSLOT * NPIXP)   // 3048 uint4 = 48768 B per buffer

typedef _Float16 f16x8 __attribute__((ext_vector_type(8)));
typedef float    f32x4 __attribute__((ext_vector_type(4)));

__device__ __forceinline__ float h2f(ushort u) {
    _Float16 h = __builtin_bit_cast(_Float16, u);
    return (float)h;
}
__device__ __forceinline__ ushort f2h(float f) {
    _Float16 h = (_Float16)f;
    return __builtin_bit_cast(ushort, h);
}
__device__ __forceinline__ uint pack2h(float a, float b) {
    return (uint)f2h(a) | ((uint)f2h(b) << 16);
}

// ---------------------------------------------------------------------------
// Derived values for one input x, packed as 12 f16 in 6 u32:
//   halves [0..10] = cubic B-spline bases 0..10 on uniform grid
//   half  [11]     = silu(x)
// Closed form: 4 nonzero bases (cell ci = floor(4x+7)), placed via 64-bit
// funnel shift. Verified R1-R8 (absmax 0.0039, passing).
// ---------------------------------------------------------------------------
__device__ __forceinline__ void derived12(float x, uint* u) {
    float si = x / (1.0f + __expf(-x));          // silu
    float t  = fmaf(x, 4.0f, 7.0f);              // (x + 1.75) / 0.25
    t = fminf(fmaxf(t, -1.0f), 15.0f);           // keep ci in [-1,15]
    float ft = floorf(t);
    int   ci = (int)ft;
    float uu = t - ft;
    float um = 1.0f - uu;
    float u2 = uu * uu, m2 = um * um;
    float u3 = u2 * uu, m3 = m2 * um;
    const float c16 = 0.16666667f, c23 = 0.66666667f;
    float w0 = u3 * c16;
    float w3 = m3 * c16;
    float w2 = fmaf(0.5f, u3, c23 - u2);
    float w1 = fmaf(0.5f, m3, c23 - m2);
    uint64_t P = (uint64_t)f2h(w3)
               | ((uint64_t)f2h(w2) << 16)
               | ((uint64_t)f2h(w1) << 32)
               | ((uint64_t)f2h(w0) << 48);
    int s = 16 * ci - 48;
    int d = s >> 6;
    int e = s & 63;
    uint64_t Q = P << e;
    uint64_t R = (P >> (63 - e)) >> 1;
    uint64_t O0 = (d == 0) ? Q : (d == -1) ? R : 0ull;
    uint64_t O1 = (d == 1) ? Q : (d ==  0) ? R : 0ull;
    uint64_t O2 = (d == 2) ? Q : (d ==  1) ? R : 0ull;
    O2 = (O2 & 0x0000ffffffffffffull) | ((uint64_t)f2h(si) << 48);
    u[0] = (uint)O0; u[1] = (uint)(O0 >> 32);
    u[2] = (uint)O1; u[3] = (uint)(O1 >> 32);
    u[4] = (uint)O2; u[5] = (uint)(O2 >> 32);
}

// ---------------------------------------------------------------------------
// Weight prep (unchanged): fp32 -> f16 MFMA A-fragment tables; zeroes the
// per-layer stats accumulators.
// ---------------------------------------------------------------------------
__global__ void __launch_bounds__(64) prep_w(
    const float* __restrict__ bw1, const float* __restrict__ sw1,
    const float* __restrict__ bw2, const float* __restrict__ sw2,
    uint4* __restrict__ wtab1, uint4* __restrict__ wtab2,
    float* __restrict__ part1, float* __restrict__ part2)
{
    const int s    = blockIdx.x;        // 0..53
    const int lane = threadIdx.x;       // 0..63
    const float* bw; const float* sw; uint4* wt;
    if (blockIdx.y == 0) { bw = bw1; sw = sw1; wt = wtab1; }
    else                 { bw = bw2; sw = sw2; wt = wtab2; }

    if (s == 0) {
        float* p = (blockIdx.y == 0) ? part1 : part2;
        p[lane] = 0.0f;
        p[64 + lane] = 0.0f;
    }

    const int co = lane & 15, q = lane >> 4;
    const int chunk = s / 27, sl = s - chunk * 27;
    uint u[4];
#pragma unroll
    for (int jj = 0; jj < 4; ++jj) {
        float w[2];
#pragma unroll
        for (int h = 0; h < 2; ++h) {
            int j   = jj * 2 + h;
            int kl  = 32 * sl + 8 * q + j;
            int tap = kl / 96;
            int r   = kl - tap * 96;
            int ci  = r / 12;
            int kv  = r - ci * 12;
            int cin = chunk * 8 + ci;
            w[h] = (kv == 11) ? bw[(co * 16 + cin) * 9 + tap]
                              : sw[(co * 176 + cin * 11 + kv) * 9 + tap];
        }
        u[jj] = pack2h(w[0], w[1]);
    }
    wt[s * 64 + lane] = make_uint4(u[0], u[1], u[2], u[3]);
}

// ---------------------------------------------------------------------------
// Role-split fused KAN conv layer.
// Waves 0-3 (tid<256): consumers -- ds_read + MFMA + epilogue.
// Waves 4-7: producers -- global load + norm/prelu + derived12 + LDS write.
// Double-buffered slot-major staging (pixel stride NPIXP=254: staged b128
// writes/reads spread across banks, minimal 2-aliasing).
// Phase machine over 2 tiles x 2 chunks (all barriers block-wide, same count
// for both roles):
//   P:S(A,0)      | P:S(A,1) C:K(A,0) | P:S(B,0) C:K(A,1)+epi1(A)
//   | P:S(B,1) C:epi2(A)+K(B,0) | C:K(B,1)+epi1(B) | C:epi2(B)
// Stats scratch is a dedicated array (no aliasing with staging buffers).
// ---------------------------------------------------------------------------
template<bool IN_H, bool OUT_H, bool NORM_IN>
__global__ __launch_bounds__(512, 2) void conv_mfma(
    const void* __restrict__ in_v,
    const uint4* __restrict__ wtab,
    void* __restrict__ out_v,
    const float* __restrict__ stats_in,
    const float* __restrict__ a_in,
    float* __restrict__ part_out)
{
    __shared__ uint4 dt16[2][BUFU];    // 97536 B (gfx950 LDS/workgroup > 64KB ok)
    __shared__ float scr[128];         // stats scratch [wv][co][{s,q}]

    const int tid  = threadIdx.x;      // 0..511
    const bool isC = tid < 256;
    const int lane = tid & 63;
    const int wv   = (tid >> 6) & 3;   // wave idx within role, 0..3
    const int m    = lane & 15;        // consumer: pixel-x
    const int q    = lane >> 4;        // consumer: k-octet
    const int ptid = tid & 255;        // producer: staging thread id
    const int by0  = blockIdx.y * TR;
    const int bxA  = blockIdx.x * 32;  // tile A x-origin
    const int bxB  = bxA + 16;         // tile B x-origin
    const int b    = blockIdx.z;

    const float*  inf = (const float*)in_v;
    const ushort* inh = (const ushort*)in_v;

    float pa = 0.0f;
    if (NORM_IN && !isC) pa = *a_in;

    f32x4 acc[3];

    // ---- producer: stage chunk c of tile at bx0t into buf ----
    auto stage = [&](int bx0t, int c, uint4* __restrict__ buf) {
        float v0[4], v1[4];
        float4 nm[4];
        uint  bo4[4];
        bool  live[4];
        // issue all global loads before any math
#pragma unroll
        for (int k = 0; k < 4; ++k) {
            int it  = ptid + k * 256;
            bool lv = (it < NPIXR * 4);
            int cp  = it & 3;              // cin pair 0..3
            int pix = it >> 2;             // 0..251
            if (!lv) pix = 0;
            int py  = pix / HTILE;
            int px  = pix - py * HTILE;
            int gy  = by0 + py - 1;
            int gx  = bx0t + px - 1;
            bool ok = lv && ((unsigned)gy < (unsigned)HW)
                         && ((unsigned)gx < (unsigned)HW);
            live[k] = lv;
            bo4[k]  = (uint)(cp * 3 * NPIXP + pix);
            float a = -1.0e9f, cc = -1.0e9f;   // pad: bases->0, silu->-0
            if (ok) {
                size_t base = ((size_t)(b * CCH + c * 8 + cp * 2) << 18)
                            + ((size_t)gy << 9) + gx;
                if (IN_H) { a = h2f(inh[base]); cc = h2f(inh[base + (1u << 18)]); }
                else      { a = inf[base];      cc = inf[base + (1u << 18)]; }
            }
            if (NORM_IN && lv)
                nm[k] = *reinterpret_cast<const float4*>(
                    &stats_in[b * 32 + (c * 8 + cp * 2) * 2]);
            v0[k] = a; v1[k] = cc;
        }
        // norm/prelu + derive + LDS write
#pragma unroll
        for (int k = 0; k < 4; ++k) {
            if (live[k]) {
                float a0 = v0[k], c0 = v1[k];
                if (NORM_IN) {
                    a0 = (a0 - nm[k].x) * nm[k].y;
                    a0 = (a0 >= 0.f) ? a0 : pa * a0;
                    c0 = (c0 - nm[k].z) * nm[k].w;
                    c0 = (c0 >= 0.f) ? c0 : pa * c0;
                }
                uint uA[6], uB[6];
                derived12(a0, uA);
                derived12(c0, uB);
                uint bo = bo4[k];
                buf[bo]             = make_uint4(uA[0], uA[1], uA[2], uA[3]);
                buf[bo + NPIXP]     = make_uint4(uA[4], uA[5], uB[0], uB[1]);
                buf[bo + 2 * NPIXP] = make_uint4(uB[2], uB[3], uB[4], uB[5]);
            }
        }
    };

    // ---- consumer: K-loop for chunk c on buf (row-register reuse) ----
    auto krun = [&](int c, const uint4* __restrict__ buf) {
        uint4 wf[27];
#pragma unroll
        for (int s = 0; s < 27; ++s) wf[s] = wtab[(c * 27 + s) * 64 + lane];
        const uint pixbase = (uint)(wv * 3 * HTILE + m);
#pragma unroll
        for (int j = 0; j < 3; ++j) {
            const uint slotoff = (uint)((j * 4 + q) * NPIXP) + pixbase;
#pragma unroll
            for (int tdx = 0; tdx < 3; ++tdx) {
                f16x8 brow[5];
#pragma unroll
                for (int r6 = 0; r6 < 5; ++r6)
                    brow[r6] = *reinterpret_cast<const f16x8*>(
                        &buf[slotoff + (uint)(r6 * HTILE + tdx)]);
#pragma unroll
                for (int tdy = 0; tdy < 3; ++tdy) {
                    const int s = (tdy * 3 + tdx) * 3 + j;
#pragma unroll
                    for (int t = 0; t < 3; ++t) {
                        acc[t] = __builtin_amdgcn_mfma_f32_16x16x32_f16(
                            __builtin_bit_cast(f16x8, wf[s]), brow[t + tdy],
                            acc[t], 0, 0, 0);
                    }
                }
            }
        }
    };

    // ---- consumer: store tile output + per-wave stats partials to scr ----
    auto epi1 = [&](int bx0t) {
#pragma unroll
        for (int t = 0; t < 3; ++t) {
            int oy = by0 + wv * 3 + t;
            if (oy < HW) {
#pragma unroll
                for (int r = 0; r < 4; ++r) {
                    int co = q * 4 + r;
                    size_t idx = ((size_t)(b * CCH + co) << 18)
                               + ((size_t)oy << 9) + (bx0t + m);
                    if (OUT_H) ((ushort*)out_v)[idx] = f2h(acc[t][r]);
                    else       ((float*)out_v)[idx]  = acc[t][r];
                }
            }
        }
        float s4[4], q4[4];
#pragma unroll
        for (int r = 0; r < 4; ++r) { s4[r] = 0.0f; q4[r] = 0.0f; }
#pragma unroll
        for (int t = 0; t < 3; ++t) {
            int oy = by0 + wv * 3 + t;
            if (oy < HW) {
#pragma unroll
                for (int r = 0; r < 4; ++r) {
                    s4[r] += acc[t][r];
                    q4[r] = fmaf(acc[t][r], acc[t][r], q4[r]);
                }
            }
        }
#pragma unroll
        for (int off = 8; off > 0; off >>= 1) {
#pragma unroll
            for (int r = 0; r < 4; ++r) {
                s4[r] += __shfl_xor(s4[r], off);
                q4[r] += __shfl_xor(q4[r], off);
            }
        }
        if (m == 0) {
#pragma unroll
            for (int r = 0; r < 4; ++r) {
                scr[(wv * 16 + q * 4 + r) * 2 + 0] = s4[r];
                scr[(wv * 16 + q * 4 + r) * 2 + 1] = q4[r];
            }
        }
    };

    // ---- consumer wave 0: fold scr + one atomic per (co,which) ----
    auto epi2 = [&]() {
        if (tid < 32) {
            int co = tid >> 1, which = tid & 1;
            float v = scr[(0 * 16 + co) * 2 + which]
                    + scr[(1 * 16 + co) * 2 + which]
                    + scr[(2 * 16 + co) * 2 + which]
                    + scr[(3 * 16 + co) * 2 + which];
            atomicAdd(&part_out[(size_t)(b * CCH + co) * 2 + which], v);
        }
    };

#define ACCZ do { _Pragma("unroll") \
    for (int t = 0; t < 3; ++t) acc[t] = f32x4{0.f, 0.f, 0.f, 0.f}; } while (0)

    // ---------------- phase machine ----------------
    if (!isC) stage(bxA, 0, dt16[0]);
    __syncthreads();                               // buf0(A,0) ready
    if (!isC) stage(bxA, 1, dt16[1]);
    else      { ACCZ; krun(0, dt16[0]); }
    __syncthreads();                               // buf1(A,1) ready; buf0 free
    if (!isC) stage(bxB, 0, dt16[0]);
    else      { krun(1, dt16[1]); epi1(bxA); }
    __syncthreads();                               // buf0(B,0) ready; scr(A) ready
    if (!isC) stage(bxB, 1, dt16[1]);
    else      { epi2(); ACCZ; krun(0, dt16[0]); }
    __syncthreads();                               // buf1(B,1) ready
    if (isC)  { krun(1, dt16[1]); epi1(bxB); }
    __syncthreads();                               // scr(B) ready
    if (isC)  epi2();
#undef ACCZ
}

// ---- stats finalize: part (sum, sumsq over 262144) -> (mean, rstd) ----
__global__ void __launch_bounds__(64) reduce_final(
    const float* __restrict__ part, float* __restrict__ stats)
{
    const int bc = threadIdx.x;   // 0..63
    const float inv = 1.0f / 262144.0f;
    float s  = part[bc * 2];
    float qq = part[bc * 2 + 1];
    float mval = s * inv;
    float var  = qq * inv - mval * mval;
    stats[bc * 2]     = mval;
    stats[bc * 2 + 1] = rsqrtf(var + 1e-5f);
}

// out = sigmoid(prelu(instancenorm(z2))) in place on d_out, float4-wide.
__global__ void __launch_bounds__(256) final_sigmoid(
    float* __restrict__ out, const float* __restrict__ stats,
    const float* __restrict__ a_ptr)
{
    const float a = *a_ptr;
    const int i4 = blockIdx.x * 256 + threadIdx.x;
    const int bc = i4 >> 16;
    const float mm = stats[bc * 2];
    const float rr = stats[bc * 2 + 1];
    float4 v = reinterpret_cast<float4*>(out)[i4];
    float t;
    t = (v.x - mm) * rr; t = (t >= 0.f) ? t : a * t; v.x = 1.0f / (1.0f + __expf(-t));
    t = (v.y - mm) * rr; t = (t >= 0.f) ? t : a * t; v.y = 1.0f / (1.0f + __expf(-t));
    t = (v.z - mm) * rr; t = (t >= 0.f) ? t : a * t; v.z = 1.0f / (1.0f + __expf(-t));
    t = (v.w - mm) * rr; t = (t >= 0.f) ? t : a * t; v.w = 1.0f / (1.0f + __expf(-t));
    reinterpret_cast<float4*>(out)[i4] = v;
}

extern "C" void kernel_launch(void* const* d_in, const int* in_sizes, int n_in,
                              void* d_out, int out_size, void* d_ws, size_t ws_size,
                              hipStream_t stream)
{
    const float* x        = (const float*)d_in[0];
    const float* base_w1  = (const float*)d_in[1];
    const float* spline_w1= (const float*)d_in[2];
    const float* prelu_a1 = (const float*)d_in[3];
    const float* base_w2  = (const float*)d_in[4];
    const float* spline_w2= (const float*)d_in[5];
    const float* prelu_a2 = (const float*)d_in[6];
    float* out_f = (float*)d_out;
    char*  wsb   = (char*)d_ws;

    // ws layout (all within 64 MiB):
    //   z1h    @ 0          : 4*16*512*512*2 = 33554432 B (f16, raw conv1 out)
    //   wtab1  @ 33554432   : 54*64*16 = 55296 B
    //   wtab2  @ 33609728   : 55296 B
    //   part1  @ 33665024   : 512 B
    //   part2  @ 33665536   : 512 B
    //   stats1 @ 33666048   : 512 B
    //   stats2 @ 33666560   : 512 B
    ushort* z1h    = (ushort*)wsb;
    uint4*  wtab1  = (uint4*)(wsb + 33554432);
    uint4*  wtab2  = (uint4*)(wsb + 33609728);
    float*  part1  = (float*)(wsb + 33665024);
    float*  part2  = (float*)(wsb + 33665536);
    float*  stats1 = (float*)(wsb + 33666048);
    float*  stats2 = (float*)(wsb + 33666560);

    dim3 cgrid(HW / 32, (HW + TR - 1) / TR, 4);   // (16,43,4), 2 tiles/block in x
    dim3 cblk(512);                               // conv only (8 waves)
    dim3 eblk(256);                               // elementwise kernels

    // weight tables for both layers + zero stats accumulators
    prep_w<<<dim3(54, 2), 64, 0, stream>>>(base_w1, spline_w1, base_w2, spline_w2,
                                           wtab1, wtab2, part1, part2);

    // ---- layer 1: x (fp32) -> z1 (f16, raw) + partial stats ----
    conv_mfma<false, true, false><<<cgrid, cblk, 0, stream>>>(
        x, wtab1, z1h, nullptr, nullptr, part1);
    reduce_final<<<1, 64, 0, stream>>>(part1, stats1);

    // ---- layer 2: y1 = prelu(norm(z1)) fused into staging; -> z2 (fp32) ----
    conv_mfma<true, false, true><<<cgrid, cblk, 0, stream>>>(
        z1h, wtab2, out_f, stats1, prelu_a1, part2);
    reduce_final<<<1, 64, 0, stream>>>(part2, stats2);

    // ---- final: norm + prelu + sigmoid in place on d_out (256-thread
    //      blocks: final_sigmoid is __launch_bounds__(256); launching it
    //      with the 512-thread conv block dim was R9's silent-failure bug) ----
    final_sigmoid<<<16384, eblk, 0, stream>>>(out_f, stats2, prelu_a2);
}

// Round 11
// 360.071 us; speedup vs baseline: 1.3276x; 1.3276x over previous
//
#include <hip/hip_runtime.h>
#include <cstddef>
#include <cstdint>

// ---------------- problem constants ----------------
#define HW    512
#define CCH   16
// conv tile: 16x16 output pixels per block, 18x18 halo (2 blocks/CU)
#define HTILE 18
#define NPIX  324          // real halo pixels (18*18)
#define NPIXS 326          // padded LDS pixel stride: 12*326 mod 32 == 8 ->
                           //   staged b128 writes hit all 32 banks per 8 lanes
#define NSLOT 12           // uint4 slots per pixel (96 f16 = 8 cins x 12 kv)

typedef _Float16 f16x8 __attribute__((ext_vector_type(8)));
typedef float    f32x4 __attribute__((ext_vector_type(4)));

__device__ __forceinline__ float h2f(ushort u) {
    _Float16 h = __builtin_bit_cast(_Float16, u);
    return (float)h;
}
__device__ __forceinline__ ushort f2h(float f) {
    _Float16 h = (_Float16)f;
    return __builtin_bit_cast(ushort, h);
}
__device__ __forceinline__ uint pack2h(float a, float b) {
    return (uint)f2h(a) | ((uint)f2h(b) << 16);
}

// ---------------------------------------------------------------------------
// Derived values for one input x, packed as 12 f16 in 6 u32:
//   halves [0..10] = cubic B-spline bases 0..10 on uniform grid
//                    g(i) = -1.75 + 0.25*i   (kv = 0..10)
//   half  [11]     = silu(x)                 (kv = 11)
// Closed form: only 4 bases are nonzero (cell ci = floor(4x+7), local u),
// standard uniform cubic blending weights, placed via 64-bit funnel shift.
// ---------------------------------------------------------------------------
__device__ __forceinline__ void derived12(float x, uint* u) {
    float si = x / (1.0f + __expf(-x));          // silu
    float t  = fmaf(x, 4.0f, 7.0f);              // (x + 1.75) / 0.25
    t = fminf(fmaxf(t, -1.0f), 15.0f);           // keep ci in [-1,15]
    float ft = floorf(t);
    int   ci = (int)ft;
    float uu = t - ft;
    float um = 1.0f - uu;
    float u2 = uu * uu, m2 = um * um;
    float u3 = u2 * uu, m3 = m2 * um;
    const float c16 = 0.16666667f, c23 = 0.66666667f;
    float w0 = u3 * c16;                          // basis at i = ci     (j=0)
    float w3 = m3 * c16;                          // basis at i = ci - 3 (j=3)
    float w2 = fmaf(0.5f, u3, c23 - u2);          // j=2
    float w1 = fmaf(0.5f, m3, c23 - m2);          // j=1
    // P = [w3, w2, w1, w0] as 4 f16, lowest half first (increasing basis idx)
    uint64_t P = (uint64_t)f2h(w3)
               | ((uint64_t)f2h(w2) << 16)
               | ((uint64_t)f2h(w1) << 32)
               | ((uint64_t)f2h(w0) << 48);
    // place P at half-offset (ci - 3) within the 12-half output field
    int s = 16 * ci - 48;                         // bit offset, multiple of 16
    int d = s >> 6;                               // word index of P start (-1..2)
    int e = s & 63;
    uint64_t Q = P << e;
    uint64_t R = (P >> (63 - e)) >> 1;            // e==0 -> 0, else P >> (64-e)
    uint64_t O0 = (d == 0) ? Q : (d == -1) ? R : 0ull;
    uint64_t O1 = (d == 1) ? Q : (d ==  0) ? R : 0ull;
    uint64_t O2 = (d == 2) ? Q : (d ==  1) ? R : 0ull;
    // half 11 is silu; also clips basis spill for ci >= 11
    O2 = (O2 & 0x0000ffffffffffffull) | ((uint64_t)f2h(si) << 48);
    u[0] = (uint)O0; u[1] = (uint)(O0 >> 32);
    u[2] = (uint)O1; u[3] = (uint)(O1 >> 32);
    u[4] = (uint)O2; u[5] = (uint)(O2 >> 32);
}

// ---------------------------------------------------------------------------
// Weight prep: fp32 (bw, sw) -> f16 MFMA A-operand fragment tables.
// Logical K (per layer): chunk(2) x [ tap(9)*96 + cin'(8)*12 + kv(12) ],
// 54 steps of 32. kv = 0..10 -> spline basis kv, kv = 11 -> base (silu) weight.
// Fragment element j of lane l at step s = W[cout=l&15][k=32s+8q+j].
// Also zeroes the per-layer stats accumulation buffers (fresh every launch).
// ---------------------------------------------------------------------------
__global__ void __launch_bounds__(64) prep_w(
    const float* __restrict__ bw1, const float* __restrict__ sw1,
    const float* __restrict__ bw2, const float* __restrict__ sw2,
    uint4* __restrict__ wtab1, uint4* __restrict__ wtab2,
    float* __restrict__ part1, float* __restrict__ part2)
{
    const int s    = blockIdx.x;        // 0..53
    const int lane = threadIdx.x;       // 0..63
    const float* bw; const float* sw; uint4* wt;
    if (blockIdx.y == 0) { bw = bw1; sw = sw1; wt = wtab1; }
    else                 { bw = bw2; sw = sw2; wt = wtab2; }

    if (s == 0) {   // zero the stats accumulators (128 floats each)
        float* p = (blockIdx.y == 0) ? part1 : part2;
        p[lane] = 0.0f;
        p[64 + lane] = 0.0f;
    }

    const int co = lane & 15, q = lane >> 4;
    const int chunk = s / 27, sl = s - chunk * 27;
    uint u[4];
#pragma unroll
    for (int jj = 0; jj < 4; ++jj) {
        float w[2];
#pragma unroll
        for (int h = 0; h < 2; ++h) {
            int j   = jj * 2 + h;
            int kl  = 32 * sl + 8 * q + j;     // k within chunk, 0..863
            int tap = kl / 96;
            int r   = kl - tap * 96;           // cin'*12 + kv
            int ci  = r / 12;
            int kv  = r - ci * 12;
            int cin = chunk * 8 + ci;
            w[h] = (kv == 11) ? bw[(co * 16 + cin) * 9 + tap]
                              : sw[(co * 176 + cin * 11 + kv) * 9 + tap];
        }
        u[jj] = pack2h(w[0], w[1]);
    }
    wt[s * 64 + lane] = make_uint4(u[0], u[1], u[2], u[3]);
}

// ---------------------------------------------------------------------------
// Fused KAN conv layer via f16 MFMA implicit GEMM -- R4 structure (best
// measured: 140us/dispatch) with two targeted changes:
//  * LDS pixel stride NPIXS=326 (12*326 mod 32 == 8): staged ds_write_b128
//    covers all 32 banks per 8-lane group -> kills the measured 2-way write
//    conflict (9.7M extra cycles/dispatch at stride 324).
//  * NORM_IN computes (mean,rstd) inline from the raw part sums (deletes the
//    reduce_final launch between the layers).
// ---------------------------------------------------------------------------
template<bool IN_H, bool OUT_H, bool NORM_IN>
__global__ __launch_bounds__(256, 2) void conv_mfma(
    const void* __restrict__ in_v,
    const uint4* __restrict__ wtab,
    void* __restrict__ out_v,
    const float* __restrict__ part_in,
    const float* __restrict__ a_in,
    float* __restrict__ part_out)
{
    __shared__ uint4 dt16[NSLOT * NPIXS];  // 62592 B
    __shared__ float sn[32];               // [cin][{mean, rstd}] for NORM_IN

    const int tid  = threadIdx.x;
    const int lane = tid & 63;
    const int wv   = tid >> 6;            // wave 0..3
    const int m    = lane & 15;           // pixel-x within tile (B/D "n" index)
    const int q    = lane >> 4;           // k-octet selector
    const int bx0  = blockIdx.x * 16;
    const int by0  = blockIdx.y * 16;
    const int b    = blockIdx.z;

    const float*  inf = (const float*)in_v;
    const ushort* inh = (const ushort*)in_v;

    float pa = 0.0f;
    if (NORM_IN) {
        pa = *a_in;
        if (tid < 32) {   // finalize prev-layer stats from raw sums
            int ci = tid >> 1;
            float s  = part_in[(b * CCH + ci) * 2];
            float qq = part_in[(b * CCH + ci) * 2 + 1];
            const float inv = 1.0f / 262144.0f;
            float mv  = s * inv;
            float var = qq * inv - mv * mv;
            sn[tid] = (tid & 1) ? rsqrtf(var + 1e-5f) : mv;
        }
        // ordered vs use by the first __syncthreads below
    }

    f32x4 acc[4];
#pragma unroll
    for (int t = 0; t < 4; ++t) acc[t] = f32x4{0.f, 0.f, 0.f, 0.f};

#pragma unroll 1
    for (int chunk = 0; chunk < 2; ++chunk) {
        __syncthreads();   // previous chunk's reads complete before overwrite

        // ---- stage derived f16 tile: items = (pix, cinpair) = 324*4 ----
        float v0[6], v1[6];
        uint  bofs[6], cps[6];
        bool  live[6];
        // phase 1: issue all global loads (12 in flight) before any math
#pragma unroll
        for (int k = 0; k < 6; ++k) {
            int it  = tid + k * 256;
            bool lv = (it < NPIX * 4);
            int cp  = it & 3;          // cin pair 0..3 -> cins 2cp, 2cp+1
            int pix = it >> 2;         // 0..323
            if (!lv) pix = 0;
            int py  = pix / 18;
            int px  = pix - py * 18;
            int gy  = by0 + py - 1;
            int gx  = bx0 + px - 1;
            bool ok = lv && ((unsigned)gy < (unsigned)HW)
                         && ((unsigned)gx < (unsigned)HW);
            live[k] = lv;
            cps[k]  = (uint)cp;
            bofs[k] = (uint)(cp * 3 * NPIXS + pix);
            float a = -1.0e9f, c = -1.0e9f;   // pad: silu->-0, bases->0
            if (ok) {
                size_t base = ((size_t)(b * CCH + chunk * 8 + cp * 2) << 18)
                            + ((size_t)gy << 9) + gx;
                if (IN_H) { a = h2f(inh[base]); c = h2f(inh[base + (1u << 18)]); }
                else      { a = inf[base];      c = inf[base + (1u << 18)]; }
            }
            v0[k] = a; v1[k] = c;
        }

        // ---- register-resident weight frags for this chunk (loads in
        //      flight while derived math runs) ----
        uint4 wf[27];
#pragma unroll
        for (int s = 0; s < 27; ++s) wf[s] = wtab[(chunk * 27 + s) * 64 + lane];

        // phase 2: (optional norm+prelu) + derive + LDS write
#pragma unroll
        for (int k = 0; k < 6; ++k) {
            if (live[k]) {
                float a0 = v0[k], c0 = v1[k];
                if (NORM_IN) {
                    int ci2 = (chunk * 8 + (int)cps[k] * 2) * 2;
                    a0 = (a0 - sn[ci2])     * sn[ci2 + 1];
                    a0 = (a0 >= 0.f) ? a0 : pa * a0;
                    c0 = (c0 - sn[ci2 + 2]) * sn[ci2 + 3];
                    c0 = (c0 >= 0.f) ? c0 : pa * c0;
                }
                uint uA[6], uB[6];
                derived12(a0, uA);      // cin = 2cp
                derived12(c0, uB);      // cin = 2cp+1
                uint bo = bofs[k];
                dt16[bo]             = make_uint4(uA[0], uA[1], uA[2], uA[3]);
                dt16[bo + NPIXS]     = make_uint4(uA[4], uA[5], uB[0], uB[1]);
                dt16[bo + 2 * NPIXS] = make_uint4(uB[2], uB[3], uB[4], uB[5]);
            }
        }
        __syncthreads();

        // ---- K loop: row-register reuse. addr (uint4 units):
        //      (4j+q)*NPIXS + (wv*4 + t + tdy)*18 + (m + tdx) ----
        const uint pixbase = (uint)(wv * 72 + m);
#pragma unroll
        for (int j = 0; j < 3; ++j) {
            const uint slotoff = (uint)((j * 4 + q) * NPIXS) + pixbase;
#pragma unroll
            for (int tdx = 0; tdx < 3; ++tdx) {
                f16x8 brow[6];
#pragma unroll
                for (int r6 = 0; r6 < 6; ++r6)
                    brow[r6] = *reinterpret_cast<const f16x8*>(
                        &dt16[slotoff + (uint)(r6 * HTILE + tdx)]);
#pragma unroll
                for (int tdy = 0; tdy < 3; ++tdy) {
                    const int s = (tdy * 3 + tdx) * 3 + j;
#pragma unroll
                    for (int t = 0; t < 4; ++t) {
                        acc[t] = __builtin_amdgcn_mfma_f32_16x16x32_f16(
                            __builtin_bit_cast(f16x8, wf[s]), brow[t + tdy],
                            acc[t], 0, 0, 0);
                    }
                }
            }
        }
    }

    // ---- store: lane l reg r -> cout = 4q+r, px = m, row = wv*4+t ----
#pragma unroll
    for (int t = 0; t < 4; ++t) {
        int oy = by0 + wv * 4 + t;
#pragma unroll
        for (int r = 0; r < 4; ++r) {
            int co = q * 4 + r;
            size_t idx = ((size_t)(b * CCH + co) << 18) + ((size_t)oy << 9) + (bx0 + m);
            if (OUT_H) ((ushort*)out_v)[idx] = f2h(acc[t][r]);
            else       ((float*)out_v)[idx]  = acc[t][r];
        }
    }

    // ---- fused instance-norm partial stats: per-(b,co) sum / sumsq ----
    float s4[4], q4[4];
#pragma unroll
    for (int r = 0; r < 4; ++r) {
        s4[r] = acc[0][r] + acc[1][r] + acc[2][r] + acc[3][r];
        q4[r] = fmaf(acc[0][r], acc[0][r],
                fmaf(acc[1][r], acc[1][r],
                fmaf(acc[2][r], acc[2][r], acc[3][r] * acc[3][r])));
    }
#pragma unroll
    for (int off = 8; off > 0; off >>= 1) {
#pragma unroll
        for (int r = 0; r < 4; ++r) {
            s4[r] += __shfl_xor(s4[r], off);
            q4[r] += __shfl_xor(q4[r], off);
        }
    }
    __syncthreads();                  // K-loop LDS reads done; reuse as scratch
    float* scr = (float*)dt16;        // [wv][co][{s,q}] = 128 floats
    if (m == 0) {
#pragma unroll
        for (int r = 0; r < 4; ++r) {
            scr[(wv * 16 + q * 4 + r) * 2 + 0] = s4[r];
            scr[(wv * 16 + q * 4 + r) * 2 + 1] = q4[r];
        }
    }
    __syncthreads();
    if (tid < 32) {
        int co = tid >> 1, which = tid & 1;
        float v = scr[(0 * 16 + co) * 2 + which] + scr[(1 * 16 + co) * 2 + which]
                + scr[(2 * 16 + co) * 2 + which] + scr[(3 * 16 + co) * 2 + which];
        atomicAdd(&part_out[(size_t)(b * CCH + co) * 2 + which], v);
    }
}

// out = sigmoid(prelu(instancenorm(z2))) in place on d_out, float4-wide.
// Stats computed inline from the raw part sums (bc is uniform per block).
__global__ void __launch_bounds__(256) final_sigmoid(
    float* __restrict__ out, const float* __restrict__ part,
    const float* __restrict__ a_ptr)
{
    const float a = *a_ptr;
    const int i4 = blockIdx.x * 256 + threadIdx.x;
    const int bc = blockIdx.x >> 8;        // 65536 float4 per bc, 256 per block
    const float inv = 1.0f / 262144.0f;
    const float s  = part[bc * 2];
    const float qq = part[bc * 2 + 1];
    const float mm = s * inv;
    const float rr = rsqrtf(qq * inv - mm * mm + 1e-5f);
    float4 v = reinterpret_cast<float4*>(out)[i4];
    float t;
    t = (v.x - mm) * rr; t = (t >= 0.f) ? t : a * t; v.x = 1.0f / (1.0f + __expf(-t));
    t = (v.y - mm) * rr; t = (t >= 0.f) ? t : a * t; v.y = 1.0f / (1.0f + __expf(-t));
    t = (v.z - mm) * rr; t = (t >= 0.f) ? t : a * t; v.z = 1.0f / (1.0f + __expf(-t));
    t = (v.w - mm) * rr; t = (t >= 0.f) ? t : a * t; v.w = 1.0f / (1.0f + __expf(-t));
    reinterpret_cast<float4*>(out)[i4] = v;
}

extern "C" void kernel_launch(void* const* d_in, const int* in_sizes, int n_in,
                              void* d_out, int out_size, void* d_ws, size_t ws_size,
                              hipStream_t stream)
{
    const float* x        = (const float*)d_in[0];
    const float* base_w1  = (const float*)d_in[1];
    const float* spline_w1= (const float*)d_in[2];
    const float* prelu_a1 = (const float*)d_in[3];
    const float* base_w2  = (const float*)d_in[4];
    const float* spline_w2= (const float*)d_in[5];
    const float* prelu_a2 = (const float*)d_in[6];
    float* out_f = (float*)d_out;
    char*  wsb   = (char*)d_ws;

    // ws layout (all within 64 MiB):
    //   z1h    @ 0          : 4*16*512*512*2 = 33554432 B (f16, raw conv1 out)
    //   wtab1  @ 33554432   : 54*64*16 = 55296 B
    //   wtab2  @ 33609728   : 55296 B
    //   part1  @ 33665024   : 512 B
    //   part2  @ 33665536   : 512 B
    ushort* z1h    = (ushort*)wsb;
    uint4*  wtab1  = (uint4*)(wsb + 33554432);
    uint4*  wtab2  = (uint4*)(wsb + 33609728);
    float*  part1  = (float*)(wsb + 33665024);
    float*  part2  = (float*)(wsb + 33665536);

    dim3 cgrid(HW / 16, HW / 16, 4);   // (32,32,4)
    dim3 cblk(256);

    // weight tables for both layers + zero stats accumulators
    prep_w<<<dim3(54, 2), 64, 0, stream>>>(base_w1, spline_w1, base_w2, spline_w2,
                                           wtab1, wtab2, part1, part2);

    // ---- layer 1: x (fp32) -> z1 (f16, raw) + raw partial stats ----
    conv_mfma<false, true, false><<<cgrid, cblk, 0, stream>>>(
        x, wtab1, z1h, nullptr, nullptr, part1);

    // ---- layer 2: y1 = prelu(norm(z1)) fused into staging (stats finalized
    //      inline from part1); -> z2 (fp32) + raw partial stats ----
    conv_mfma<true, false, true><<<cgrid, cblk, 0, stream>>>(
        z1h, wtab2, out_f, part1, prelu_a1, part2);

    // ---- final: norm + prelu + sigmoid in place on d_out (stats inline) ----
    final_sigmoid<<<16384, cblk, 0, stream>>>(out_f, part2, prelu_a2);
}